// Round 3
// baseline (10461.054 us; speedup 1.0000x reference)
//
#include <hip/hip_runtime.h>
#include <hip/hip_bf16.h>

#define B_ROWS 16384
#define M_DIM  256
#define N_DIM  1024
#define DEPTH  16

// ws layout in floats (only AT/WT; u lives in d_out)
#define AT_OFF 0                          // [1024][256]   A^T
#define WT_OFF (262144)                   // [16][256][1024]  W[i]^T
#define WS_NEED_BYTES ((size_t)(262144 + 16 * 262144) * 4)

// double4 accumulate += (float scalar) * (float4)
#define DFMA4(acc, s, v) do { \
    (acc).x += (double)(s) * (double)(v).x; \
    (acc).y += (double)(s) * (double)(v).y; \
    (acc).z += (double)(s) * (double)(v).z; \
    (acc).w += (double)(s) * (double)(v).w; } while (0)

__device__ __forceinline__ float shrink_one(float v, float t, float thrv) {
    float a = fabsf(v);
    return (a >= thrv) ? v : copysignf(fmaxf(a - t, 0.0f), v);
}

// in: [S][R][C] -> out: [S][C][R]
__global__ void transpose_kernel(const float* __restrict__ in, float* __restrict__ out,
                                 int R, int C) {
    __shared__ float tile[32][33];
    int s = blockIdx.z;
    const float* ip = in + (size_t)s * R * C;
    float* op = out + (size_t)s * R * C;
    int c0 = blockIdx.x * 32, r0 = blockIdx.y * 32;
    int tx = threadIdx.x, ty = threadIdx.y;  // 32 x 8
#pragma unroll
    for (int k = 0; k < 4; ++k)
        tile[ty + 8 * k][tx] = ip[(size_t)(r0 + ty + 8 * k) * C + (c0 + tx)];
    __syncthreads();
#pragma unroll
    for (int k = 0; k < 4; ++k)
        op[(size_t)(c0 + ty + 8 * k) * R + (r0 + tx)] = tile[tx][ty + 8 * k];
}

__global__ void zero_kernel(float* __restrict__ p, int n) {
    int i = blockIdx.x * blockDim.x + threadIdx.x;
    int stride = gridDim.x * blockDim.x;
    for (; i < n; i += stride) p[i] = 0.0f;
}

// A^T[n][4*m4 .. 4*m4+3]; T: from AT [1024][256]; !T: from A [256][1024]
template <bool T>
__device__ __forceinline__ float4 loadAT(const float* __restrict__ p, int n, int m4) {
    if constexpr (T) {
        return ((const float4*)p)[n * 64 + m4];
    } else {
        float4 r;
        r.x = p[(size_t)(4 * m4 + 0) * N_DIM + n];
        r.y = p[(size_t)(4 * m4 + 1) * N_DIM + n];
        r.z = p[(size_t)(4 * m4 + 2) * N_DIM + n];
        r.w = p[(size_t)(4 * m4 + 3) * N_DIM + n];
        return r;
    }
}

// W[i]^T[m][4*n4 .. 4*n4+3]; T: from WT [256][1024]; !T: from W[i] [1024][256]
template <bool T>
__device__ __forceinline__ float4 loadWT(const float* __restrict__ p, int m, int n4) {
    if constexpr (T) {
        return ((const float4*)p)[m * 256 + n4];
    } else {
        float4 r;
        r.x = p[(size_t)(4 * n4 + 0) * M_DIM + m];
        r.y = p[(size_t)(4 * n4 + 1) * M_DIM + m];
        r.z = p[(size_t)(4 * n4 + 2) * M_DIM + m];
        r.w = p[(size_t)(4 * n4 + 3) * M_DIM + m];
        return r;
    }
}

// One LISTA-CPSS iteration, fused: r = x - u A^T ; v = u + r W^T ; select ; shrink
// f64 accumulation so v matches the true dot product to f32 rounding (mask
// stability: the support-selection mask compares |v| to an exact per-row
// order statistic; f32-chain accumulation error (~2e-6) caused a mask flip).
// Block: 256 threads (4 waves), 8 rows per block. U == d_out (f32 state + output).
template <bool T>
__global__ __launch_bounds__(256)
void lista_iter_kernel(const float* __restrict__ x,
                       const float* __restrict__ Ap,    // AT [1024][256] or A [256][1024]
                       const float* __restrict__ Wp,    // WT_i [256][1024] or W_i [1024][256]
                       const float* __restrict__ thr_all,
                       float* __restrict__ U,           // [16384][1024] f32 (= d_out)
                       int iter, int kth) {
    __shared__ float u_s[8][1024];
    __shared__ float r_s[8][256];
    __shared__ float tau_s[8];

    const int tid  = threadIdx.x;
    const int lane = tid & 63;
    const int wave = tid >> 6;
    const int row0 = blockIdx.x * 8;
    const float t  = thr_all[iter];

    // ---- load u block (coalesced float4) ----
    {
        const float4* Ug4 = (const float4*)(U + (size_t)row0 * N_DIM);
        float4* us4 = (float4*)(&u_s[0][0]);
#pragma unroll
        for (int c = 0; c < 8; ++c) us4[tid + 256 * c] = Ug4[tid + 256 * c];
    }
    __syncthreads();

    // ---- phase r: r[8][256] = x - u @ A^T (K = 1024), f64 accum ----
    {
        double4 acc0 = {0, 0, 0, 0}, acc1 = {0, 0, 0, 0};
        const float4* u0p = (const float4*)&u_s[wave][0];
        const float4* u1p = (const float4*)&u_s[wave + 4][0];
        for (int n4 = 0; n4 < 256; ++n4) {
            float4 u0 = u0p[n4];
            float4 u1 = u1p[n4];
            float4 a0 = loadAT<T>(Ap, 4 * n4 + 0, lane);
            float4 a1 = loadAT<T>(Ap, 4 * n4 + 1, lane);
            float4 a2 = loadAT<T>(Ap, 4 * n4 + 2, lane);
            float4 a3 = loadAT<T>(Ap, 4 * n4 + 3, lane);
            DFMA4(acc0, u0.x, a0); DFMA4(acc0, u0.y, a1); DFMA4(acc0, u0.z, a2); DFMA4(acc0, u0.w, a3);
            DFMA4(acc1, u1.x, a0); DFMA4(acc1, u1.y, a1); DFMA4(acc1, u1.z, a2); DFMA4(acc1, u1.w, a3);
        }
        float4 xv0 = ((const float4*)(x + (size_t)(row0 + wave) * M_DIM))[lane];
        float4 xv1 = ((const float4*)(x + (size_t)(row0 + wave + 4) * M_DIM))[lane];
        float4 rv0, rv1;
        rv0.x = (float)((double)xv0.x - acc0.x);
        rv0.y = (float)((double)xv0.y - acc0.y);
        rv0.z = (float)((double)xv0.z - acc0.z);
        rv0.w = (float)((double)xv0.w - acc0.w);
        rv1.x = (float)((double)xv1.x - acc1.x);
        rv1.y = (float)((double)xv1.y - acc1.y);
        rv1.z = (float)((double)xv1.z - acc1.z);
        rv1.w = (float)((double)xv1.w - acc1.w);
        ((float4*)&r_s[wave][0])[lane] = rv0;
        ((float4*)&r_s[wave + 4][0])[lane] = rv1;
    }
    __syncthreads();

    // ---- phase v: v[8][1024] = u + r @ W[i]^T (K = 256), f64 accum, into u_s ----
    {
        const float4* r0p = (const float4*)&r_s[wave][0];
        const float4* r1p = (const float4*)&r_s[wave + 4][0];
        float4* u0p = (float4*)&u_s[wave][0];
        float4* u1p = (float4*)&u_s[wave + 4][0];
#pragma unroll 1
        for (int q = 0; q < 4; ++q) {
            const int n4 = lane + 64 * q;  // float4 col index in [0,256)
            double4 acc0 = {0, 0, 0, 0}, acc1 = {0, 0, 0, 0};
            for (int m4 = 0; m4 < 64; ++m4) {
                float4 r0 = r0p[m4];
                float4 r1 = r1p[m4];
                float4 w0 = loadWT<T>(Wp, 4 * m4 + 0, n4);
                float4 w1 = loadWT<T>(Wp, 4 * m4 + 1, n4);
                float4 w2 = loadWT<T>(Wp, 4 * m4 + 2, n4);
                float4 w3 = loadWT<T>(Wp, 4 * m4 + 3, n4);
                DFMA4(acc0, r0.x, w0); DFMA4(acc0, r0.y, w1); DFMA4(acc0, r0.z, w2); DFMA4(acc0, r0.w, w3);
                DFMA4(acc1, r1.x, w0); DFMA4(acc1, r1.y, w1); DFMA4(acc1, r1.z, w2); DFMA4(acc1, r1.w, w3);
            }
            float4 uv0 = u0p[n4];
            uv0.x = (float)((double)uv0.x + acc0.x);
            uv0.y = (float)((double)uv0.y + acc0.y);
            uv0.z = (float)((double)uv0.z + acc0.z);
            uv0.w = (float)((double)uv0.w + acc0.w);
            u0p[n4] = uv0;
            float4 uv1 = u1p[n4];
            uv1.x = (float)((double)uv1.x + acc1.x);
            uv1.y = (float)((double)uv1.y + acc1.y);
            uv1.z = (float)((double)uv1.z + acc1.z);
            uv1.w = (float)((double)uv1.w + acc1.w);
            u1p[n4] = uv1;
        }
    }
    __syncthreads();

    // ---- phase select: per row, exact k-th largest of |v| via bitwise binary search ----
    {
#pragma unroll 1
        for (int rr = 0; rr < 2; ++rr) {
            const int row = wave + rr * 4;
            unsigned key[16];
#pragma unroll
            for (int j = 0; j < 16; ++j)
                key[j] = __float_as_uint(u_s[row][lane + 64 * j]) & 0x7fffffffu;
            unsigned p = 0;
#pragma unroll 1
            for (int b = 30; b >= 0; --b) {
                const unsigned cand = p | (1u << b);
                int cnt = 0;
#pragma unroll
                for (int j = 0; j < 16; ++j) cnt += (key[j] >= cand) ? 1 : 0;
#pragma unroll
                for (int off = 32; off; off >>= 1) cnt += __shfl_xor(cnt, off);
                if (cnt >= kth) p = cand;  // cnt uniform across lanes
            }
            if (lane == 0) tau_s[row] = __uint_as_float(p);
        }
    }
    __syncthreads();

    // ---- phase shrink + store (f32, into U == d_out) ----
    {
        const float4* us4 = (const float4*)&u_s[0][0];
        float4* Uw = (float4*)(U + (size_t)row0 * N_DIM);
#pragma unroll 1
        for (int c = 0; c < 8; ++c) {
            const int idx = tid + 256 * c;   // float4 index within block tile
            const int row = idx >> 8;        // 256 float4 per row
            const float thrv = fmaxf(t, tau_s[row]);
            float4 v = us4[idx];
            float4 o;
            o.x = shrink_one(v.x, t, thrv);
            o.y = shrink_one(v.y, t, thrv);
            o.z = shrink_one(v.z, t, thrv);
            o.w = shrink_one(v.w, t, thrv);
            Uw[idx] = o;
        }
    }
}

extern "C" void kernel_launch(void* const* d_in, const int* in_sizes, int n_in,
                              void* d_out, int out_size, void* d_ws, size_t ws_size,
                              hipStream_t stream) {
    const float* x   = (const float*)d_in[0];  // [16384][256]
    const float* A   = (const float*)d_in[1];  // [256][1024]
    const float* W   = (const float*)d_in[2];  // [16][1024][256]
    const float* thr = (const float*)d_in[3];  // [16]

    float* U = (float*)d_out;                  // u state lives in d_out (f32)
    const bool use_t = (ws_size >= WS_NEED_BYTES);

    // k-th largest table: k = 1024 - (ceil((100-p)/100*1024) - 1), p = clip((i+1)*1.2, 0, 5)
    static const int ktab[DEPTH] = {13, 25, 37, 50, 52, 52, 52, 52,
                                    52, 52, 52, 52, 52, 52, 52, 52};

    zero_kernel<<<1024, 256, 0, stream>>>(U, B_ROWS * N_DIM);

    if (use_t) {
        float* ws = (float*)d_ws;
        float* AT = ws + AT_OFF;
        float* WT = ws + WT_OFF;
        dim3 tb(32, 8);
        transpose_kernel<<<dim3(N_DIM / 32, M_DIM / 32, 1), tb, 0, stream>>>(A, AT, M_DIM, N_DIM);
        transpose_kernel<<<dim3(M_DIM / 32, N_DIM / 32, DEPTH), tb, 0, stream>>>(W, WT, N_DIM, M_DIM);
        for (int it = 0; it < DEPTH; ++it) {
            lista_iter_kernel<true><<<B_ROWS / 8, 256, 0, stream>>>(
                x, AT, WT + (size_t)it * M_DIM * N_DIM, thr, U, it, ktab[it]);
        }
    } else {
        for (int it = 0; it < DEPTH; ++it) {
            lista_iter_kernel<false><<<B_ROWS / 8, 256, 0, stream>>>(
                x, A, W + (size_t)it * N_DIM * M_DIM, thr, U, it, ktab[it]);
        }
    }
}

// Round 4
// 3864.892 us; speedup vs baseline: 2.7067x; 2.7067x over previous
//
#include <hip/hip_runtime.h>
#include <hip/hip_bf16.h>

#define B_ROWS 16384
#define M_DIM  256
#define N_DIM  1024
#define DEPTH  16

typedef __attribute__((ext_vector_type(8))) short short8;
typedef __attribute__((ext_vector_type(4))) float f32x4;
typedef __attribute__((ext_vector_type(2))) float f32x2;

// ---------------- fast path ws layout (bytes) ----------------
// ATp: frag-ordered bf16 planes of A^T  : 16 tile * 32 kc * 3 p * 512 ushort = 1,572,864 B
// WTp: frag-ordered bf16 planes of W^T  : 16 it * 64 tile * 8 kc * 3 p * 512 = 25,165,824 B
// R  : r scratch f32 [16384][256]                                  = 16,777,216 B
#define ATP_USHORTS (16 * 32 * 3 * 512)
#define WTP_USHORTS (16 * 64 * 8 * 3 * 512)
#define ATP_OFF_B   0
#define WTP_OFF_B   (1572864)
#define R_OFF_B     (1572864 + 25165824)
#define WS_FAST_NEED ((size_t)(1572864 + 25165824 + 16777216))

// ---------------- fallback (round-3) ws layout ----------------
#define AT_OFF 0
#define WT_OFF (262144)
#define WS_OLD_NEED ((size_t)(262144 + 16 * 262144) * 4)

// ================= helpers =================
__device__ __forceinline__ unsigned short bf16r(float f) {
    unsigned u = __float_as_uint(f);
    u += 0x7fffu + ((u >> 16) & 1u);
    return (unsigned short)(u >> 16);
}
__device__ __forceinline__ float bf2f(unsigned short h) {
    return __uint_as_float(((unsigned)h) << 16);
}
__device__ __forceinline__ void split3(float x, unsigned short& h, unsigned short& m,
                                       unsigned short& lo) {
    h = bf16r(x); float r1 = x - bf2f(h);
    m = bf16r(r1); float r2 = r1 - bf2f(m);
    lo = bf16r(r2);
}
__device__ __forceinline__ f32x4 MF(short8 a, short8 b, f32x4 c) {
    return __builtin_amdgcn_mfma_f32_16x16x32_bf16(a, b, c, 0, 0, 0);
}
__device__ __forceinline__ float shrink_one(float v, float t, float thrv) {
    float a = fabsf(v);
    return (a >= thrv) ? v : copysignf(fmaxf(a - t, 0.0f), v);
}

// ================= prep kernels =================
// B-frag layout per (tile, kc): 3 planes x 64 lanes x 8 bf16 (16B per lane).
// frag value = OP[k = kc*32 + (lane>>4)*8 + j][col = tile*16 + (lane&15)]
__global__ void prep_a_kernel(const float* __restrict__ A, unsigned short* __restrict__ ATp) {
    int g = blockIdx.x * 256 + threadIdx.x;        // 16*32*64 = 32768
    if (g >= 16 * 32 * 64) return;
    int l = g & 63, kc = (g >> 6) & 31, tile = g >> 11;
    int row = tile * 16 + (l & 15);                // A row m  (output col of G1)
    int k0 = kc * 32 + ((l >> 4) << 3);            // A col n  (K index)
    unsigned short h[8], m[8], lo[8];
#pragma unroll
    for (int j = 0; j < 8; ++j) split3(A[(size_t)row * N_DIM + k0 + j], h[j], m[j], lo[j]);
    size_t base = ((size_t)(tile * 32 + kc) * 3) * 512 + l * 8;
#pragma unroll
    for (int j = 0; j < 8; ++j) {
        ATp[base + j] = h[j];
        ATp[base + 512 + j] = m[j];
        ATp[base + 1024 + j] = lo[j];
    }
}

__global__ void prep_w_kernel(const float* __restrict__ W, unsigned short* __restrict__ WTp) {
    int g = blockIdx.x * 256 + threadIdx.x;        // 16*64*8*64 = 524288
    if (g >= 16 * 64 * 8 * 64) return;
    int l = g & 63, kc = (g >> 6) & 7, tile = (g >> 9) & 63, it = g >> 15;
    int n = tile * 16 + (l & 15);                  // output col of G2 (W row)
    int m0 = kc * 32 + ((l >> 4) << 3);            // K index (W col)
    const float* Wi = W + (size_t)it * N_DIM * M_DIM;
    unsigned short h[8], m[8], lo[8];
#pragma unroll
    for (int j = 0; j < 8; ++j) split3(Wi[(size_t)n * M_DIM + m0 + j], h[j], m[j], lo[j]);
    size_t base = (((size_t)(it * 64 + tile) * 8 + kc) * 3) * 512 + l * 8;
#pragma unroll
    for (int j = 0; j < 8; ++j) {
        WTp[base + j] = h[j];
        WTp[base + 512 + j] = m[j];
        WTp[base + 1024 + j] = lo[j];
    }
}

// ================= staging (shared by G1/G2) =================
// LDS activation chunk: [64 rows][32 k] bf16 x 3 planes, row stride padded to 40
// ushorts (80B) -> 2-way banks max on frag reads.
#define ST_STRIDE 40
__device__ __forceinline__ void split_write_lds(unsigned short* buf0, unsigned short* buf1,
                                                unsigned short* buf2, int srow, int kp,
                                                f32x2 v) {
    unsigned short h0, m0, l0, h1, m1, l1;
    split3(v.x, h0, m0, l0);
    split3(v.y, h1, m1, l1);
    unsigned idx = srow * ST_STRIDE + kp;          // even
    *(unsigned*)&buf0[idx] = (unsigned)h0 | ((unsigned)h1 << 16);
    *(unsigned*)&buf1[idx] = (unsigned)m0 | ((unsigned)m1 << 16);
    *(unsigned*)&buf2[idx] = (unsigned)l0 | ((unsigned)l1 << 16);
}

// ================= G1: R = x - U * A^T  (K = 1024) =================
// grid 256, block 1024 (16 waves, 4M x 4N). BM=64, BN=256.
__global__ __launch_bounds__(1024, 4)
void g1_kernel(const float* __restrict__ U, const float* __restrict__ x,
               const unsigned short* __restrict__ ATp, float* __restrict__ Rout) {
    __shared__ unsigned short up[2][3][64 * ST_STRIDE];
    const int tid = threadIdx.x;
    const int l = tid & 63, w = tid >> 6;
    const int wm = w >> 2, wn = w & 3;
    const int row0 = blockIdx.x * 64;
    const int srow = tid >> 4, kp = (tid & 15) * 2;
    const int arow = 16 * wm + (l & 15);
    const int akl = ((l >> 4) << 3);

    f32x4 acc_hi[4], acc_rest[4];
    double acc64[4][4];
#pragma unroll
    for (int t = 0; t < 4; ++t) {
        acc_hi[t] = (f32x4){0, 0, 0, 0};
        acc_rest[t] = (f32x4){0, 0, 0, 0};
#pragma unroll
        for (int e = 0; e < 4; ++e) acc64[t][e] = 0.0;
    }

    // prologue: stage chunk 0
    {
        f32x2 st = *(const f32x2*)&U[(size_t)(row0 + srow) * N_DIM + kp];
        split_write_lds(up[0][0], up[0][1], up[0][2], srow, kp, st);
    }
    __syncthreads();

    for (int kc = 0; kc < 32; ++kc) {
        const int cur = kc & 1;
        f32x2 nx;
        if (kc + 1 < 32)
            nx = *(const f32x2*)&U[(size_t)(row0 + srow) * N_DIM + (kc + 1) * 32 + kp];

        short8 ah = *(const short8*)&up[cur][0][arow * ST_STRIDE + akl];
        short8 am = *(const short8*)&up[cur][1][arow * ST_STRIDE + akl];
        short8 al = *(const short8*)&up[cur][2][arow * ST_STRIDE + akl];
#pragma unroll
        for (int tt = 0; tt < 4; ++tt) {
            const int tile = 4 * wn + tt;
            const unsigned bo = ((unsigned)(tile * 32 + kc) * 3) * 512 + l * 8;
            short8 bh = *(const short8*)&ATp[bo];
            short8 bm = *(const short8*)&ATp[bo + 512];
            short8 bl = *(const short8*)&ATp[bo + 1024];
            acc_hi[tt] = MF(ah, bh, acc_hi[tt]);
            acc_rest[tt] = MF(ah, bm, acc_rest[tt]);
            acc_rest[tt] = MF(am, bh, acc_rest[tt]);
            acc_rest[tt] = MF(am, bm, acc_rest[tt]);
            acc_rest[tt] = MF(ah, bl, acc_rest[tt]);
            acc_rest[tt] = MF(al, bh, acc_rest[tt]);
        }
        if ((kc & 3) == 3) {
#pragma unroll
            for (int tt = 0; tt < 4; ++tt) {
#pragma unroll
                for (int e = 0; e < 4; ++e) acc64[tt][e] += (double)acc_hi[tt][e];
                acc_hi[tt] = (f32x4){0, 0, 0, 0};
            }
        }
        if (kc + 1 < 32) {
            __syncthreads();
            split_write_lds(up[cur ^ 1][0], up[cur ^ 1][1], up[cur ^ 1][2], srow, kp, nx);
            __syncthreads();
        }
    }
#pragma unroll
    for (int tt = 0; tt < 4; ++tt) {
        const int col = 64 * wn + 16 * tt + (l & 15);
#pragma unroll
        for (int e = 0; e < 4; ++e) {
            const int row = row0 + 16 * wm + ((l >> 4) << 2) + e;
            double tot = acc64[tt][e] + (double)acc_rest[tt][e];
            Rout[(size_t)row * M_DIM + col] =
                (float)((double)x[(size_t)row * M_DIM + col] - tot);
        }
    }
}

// ================= G2: V = U + Asrc * W^T (K = 256), in-place V==U =================
// grid 1024 (256 panels x 4 col-groups), block 1024.
__global__ __launch_bounds__(1024, 4)
void g2_kernel(const float* __restrict__ Asrc, const unsigned short* __restrict__ WTpi,
               float* UV, int first) {
    __shared__ unsigned short rp[2][3][64 * ST_STRIDE];
    const int tid = threadIdx.x;
    const int l = tid & 63, w = tid >> 6;
    const int wm = w >> 2, wn = w & 3;
    const int panel = blockIdx.x >> 2, cg = blockIdx.x & 3;
    const int row0 = panel * 64;
    const int srow = tid >> 4, kp = (tid & 15) * 2;
    const int arow = 16 * wm + (l & 15);
    const int akl = ((l >> 4) << 3);

    f32x4 acc_hi[4], acc_rest[4];
    double acc64[4][4];
#pragma unroll
    for (int t = 0; t < 4; ++t) {
        acc_hi[t] = (f32x4){0, 0, 0, 0};
        acc_rest[t] = (f32x4){0, 0, 0, 0};
#pragma unroll
        for (int e = 0; e < 4; ++e) acc64[t][e] = 0.0;
    }

    {
        f32x2 st = *(const f32x2*)&Asrc[(size_t)(row0 + srow) * M_DIM + kp];
        split_write_lds(rp[0][0], rp[0][1], rp[0][2], srow, kp, st);
    }
    __syncthreads();

    for (int kc = 0; kc < 8; ++kc) {
        const int cur = kc & 1;
        f32x2 nx;
        if (kc + 1 < 8)
            nx = *(const f32x2*)&Asrc[(size_t)(row0 + srow) * M_DIM + (kc + 1) * 32 + kp];

        short8 ah = *(const short8*)&rp[cur][0][arow * ST_STRIDE + akl];
        short8 am = *(const short8*)&rp[cur][1][arow * ST_STRIDE + akl];
        short8 al = *(const short8*)&rp[cur][2][arow * ST_STRIDE + akl];
#pragma unroll
        for (int tt = 0; tt < 4; ++tt) {
            const int tile = cg * 16 + 4 * wn + tt;
            const unsigned bo = ((unsigned)(tile * 8 + kc) * 3) * 512 + l * 8;
            short8 bh = *(const short8*)&WTpi[bo];
            short8 bm = *(const short8*)&WTpi[bo + 512];
            short8 bl = *(const short8*)&WTpi[bo + 1024];
            acc_hi[tt] = MF(ah, bh, acc_hi[tt]);
            acc_rest[tt] = MF(ah, bm, acc_rest[tt]);
            acc_rest[tt] = MF(am, bh, acc_rest[tt]);
            acc_rest[tt] = MF(am, bm, acc_rest[tt]);
            acc_rest[tt] = MF(ah, bl, acc_rest[tt]);
            acc_rest[tt] = MF(al, bh, acc_rest[tt]);
        }
        if ((kc & 3) == 3) {
#pragma unroll
            for (int tt = 0; tt < 4; ++tt) {
#pragma unroll
                for (int e = 0; e < 4; ++e) acc64[tt][e] += (double)acc_hi[tt][e];
                acc_hi[tt] = (f32x4){0, 0, 0, 0};
            }
        }
        if (kc + 1 < 8) {
            __syncthreads();
            split_write_lds(rp[cur ^ 1][0], rp[cur ^ 1][1], rp[cur ^ 1][2], srow, kp, nx);
            __syncthreads();
        }
    }
#pragma unroll
    for (int tt = 0; tt < 4; ++tt) {
        const int col = cg * 256 + 64 * wn + 16 * tt + (l & 15);
#pragma unroll
        for (int e = 0; e < 4; ++e) {
            const int row = row0 + 16 * wm + ((l >> 4) << 2) + e;
            double tot = acc64[tt][e] + (double)acc_rest[tt][e];
            float vv = first ? (float)tot
                             : (float)((double)UV[(size_t)row * N_DIM + col] + tot);
            UV[(size_t)row * N_DIM + col] = vv;
        }
    }
}

// ================= S: exact per-row k-th largest select + shrink, in place =================
__global__ __launch_bounds__(256)
void s_kernel(float* UV, const float* __restrict__ thr_all, int iter, int kth) {
    __shared__ float v_s[8][1024];
    __shared__ float tau_s[8];
    const int tid = threadIdx.x;
    const int lane = tid & 63;
    const int wave = tid >> 6;
    const int row0 = blockIdx.x * 8;
    const float t = thr_all[iter];

    {
        const float4* Vg4 = (const float4*)(UV + (size_t)row0 * N_DIM);
        float4* vs4 = (float4*)(&v_s[0][0]);
#pragma unroll
        for (int c = 0; c < 8; ++c) vs4[tid + 256 * c] = Vg4[tid + 256 * c];
    }
    __syncthreads();

#pragma unroll 1
    for (int rr = 0; rr < 2; ++rr) {
        const int row = wave + rr * 4;
        unsigned key[16];
#pragma unroll
        for (int j = 0; j < 16; ++j)
            key[j] = __float_as_uint(v_s[row][lane + 64 * j]) & 0x7fffffffu;
        unsigned p = 0;
#pragma unroll 1
        for (int b = 30; b >= 0; --b) {
            const unsigned cand = p | (1u << b);
            int cnt = 0;
#pragma unroll
            for (int j = 0; j < 16; ++j) cnt += (key[j] >= cand) ? 1 : 0;
#pragma unroll
            for (int off = 32; off; off >>= 1) cnt += __shfl_xor(cnt, off);
            if (cnt >= kth) p = cand;
        }
        if (lane == 0) tau_s[row] = __uint_as_float(p);
    }
    __syncthreads();

    {
        const float4* vs4 = (const float4*)&v_s[0][0];
        float4* Uw = (float4*)(UV + (size_t)row0 * N_DIM);
#pragma unroll 1
        for (int c = 0; c < 8; ++c) {
            const int idx = tid + 256 * c;
            const int row = idx >> 8;
            const float thrv = fmaxf(t, tau_s[row]);
            float4 v = vs4[idx];
            float4 o;
            o.x = shrink_one(v.x, t, thrv);
            o.y = shrink_one(v.y, t, thrv);
            o.z = shrink_one(v.z, t, thrv);
            o.w = shrink_one(v.w, t, thrv);
            Uw[idx] = o;
        }
    }
}

// =====================================================================
// ===================== round-3 fallback kernels ======================
// =====================================================================
#define DFMA4(acc, s, v) do { \
    (acc).x += (double)(s) * (double)(v).x; \
    (acc).y += (double)(s) * (double)(v).y; \
    (acc).z += (double)(s) * (double)(v).z; \
    (acc).w += (double)(s) * (double)(v).w; } while (0)

__global__ void transpose_kernel(const float* __restrict__ in, float* __restrict__ out,
                                 int R, int C) {
    __shared__ float tile[32][33];
    int s = blockIdx.z;
    const float* ip = in + (size_t)s * R * C;
    float* op = out + (size_t)s * R * C;
    int c0 = blockIdx.x * 32, r0 = blockIdx.y * 32;
    int tx = threadIdx.x, ty = threadIdx.y;
#pragma unroll
    for (int k = 0; k < 4; ++k)
        tile[ty + 8 * k][tx] = ip[(size_t)(r0 + ty + 8 * k) * C + (c0 + tx)];
    __syncthreads();
#pragma unroll
    for (int k = 0; k < 4; ++k)
        op[(size_t)(c0 + ty + 8 * k) * R + (r0 + tx)] = tile[tx][ty + 8 * k];
}

__global__ void zero_kernel(float* __restrict__ p, int n) {
    int i = blockIdx.x * blockDim.x + threadIdx.x;
    int stride = gridDim.x * blockDim.x;
    for (; i < n; i += stride) p[i] = 0.0f;
}

template <bool T>
__device__ __forceinline__ float4 loadAT(const float* __restrict__ p, int n, int m4) {
    if constexpr (T) {
        return ((const float4*)p)[n * 64 + m4];
    } else {
        float4 r;
        r.x = p[(size_t)(4 * m4 + 0) * N_DIM + n];
        r.y = p[(size_t)(4 * m4 + 1) * N_DIM + n];
        r.z = p[(size_t)(4 * m4 + 2) * N_DIM + n];
        r.w = p[(size_t)(4 * m4 + 3) * N_DIM + n];
        return r;
    }
}
template <bool T>
__device__ __forceinline__ float4 loadWT(const float* __restrict__ p, int m, int n4) {
    if constexpr (T) {
        return ((const float4*)p)[m * 256 + n4];
    } else {
        float4 r;
        r.x = p[(size_t)(4 * n4 + 0) * M_DIM + m];
        r.y = p[(size_t)(4 * n4 + 1) * M_DIM + m];
        r.z = p[(size_t)(4 * n4 + 2) * M_DIM + m];
        r.w = p[(size_t)(4 * n4 + 3) * M_DIM + m];
        return r;
    }
}

template <bool T>
__global__ __launch_bounds__(256)
void lista_iter_kernel(const float* __restrict__ x, const float* __restrict__ Ap,
                       const float* __restrict__ Wp, const float* __restrict__ thr_all,
                       float* __restrict__ U, int iter, int kth) {
    __shared__ float u_s[8][1024];
    __shared__ float r_s[8][256];
    __shared__ float tau_s[8];
    const int tid = threadIdx.x;
    const int lane = tid & 63;
    const int wave = tid >> 6;
    const int row0 = blockIdx.x * 8;
    const float t = thr_all[iter];
    {
        const float4* Ug4 = (const float4*)(U + (size_t)row0 * N_DIM);
        float4* us4 = (float4*)(&u_s[0][0]);
#pragma unroll
        for (int c = 0; c < 8; ++c) us4[tid + 256 * c] = Ug4[tid + 256 * c];
    }
    __syncthreads();
    {
        double4 acc0 = {0, 0, 0, 0}, acc1 = {0, 0, 0, 0};
        const float4* u0p = (const float4*)&u_s[wave][0];
        const float4* u1p = (const float4*)&u_s[wave + 4][0];
        for (int n4 = 0; n4 < 256; ++n4) {
            float4 u0 = u0p[n4];
            float4 u1 = u1p[n4];
            float4 a0 = loadAT<T>(Ap, 4 * n4 + 0, lane);
            float4 a1 = loadAT<T>(Ap, 4 * n4 + 1, lane);
            float4 a2 = loadAT<T>(Ap, 4 * n4 + 2, lane);
            float4 a3 = loadAT<T>(Ap, 4 * n4 + 3, lane);
            DFMA4(acc0, u0.x, a0); DFMA4(acc0, u0.y, a1); DFMA4(acc0, u0.z, a2); DFMA4(acc0, u0.w, a3);
            DFMA4(acc1, u1.x, a0); DFMA4(acc1, u1.y, a1); DFMA4(acc1, u1.z, a2); DFMA4(acc1, u1.w, a3);
        }
        float4 xv0 = ((const float4*)(x + (size_t)(row0 + wave) * M_DIM))[lane];
        float4 xv1 = ((const float4*)(x + (size_t)(row0 + wave + 4) * M_DIM))[lane];
        float4 rv0, rv1;
        rv0.x = (float)((double)xv0.x - acc0.x);
        rv0.y = (float)((double)xv0.y - acc0.y);
        rv0.z = (float)((double)xv0.z - acc0.z);
        rv0.w = (float)((double)xv0.w - acc0.w);
        rv1.x = (float)((double)xv1.x - acc1.x);
        rv1.y = (float)((double)xv1.y - acc1.y);
        rv1.z = (float)((double)xv1.z - acc1.z);
        rv1.w = (float)((double)xv1.w - acc1.w);
        ((float4*)&r_s[wave][0])[lane] = rv0;
        ((float4*)&r_s[wave + 4][0])[lane] = rv1;
    }
    __syncthreads();
    {
        const float4* r0p = (const float4*)&r_s[wave][0];
        const float4* r1p = (const float4*)&r_s[wave + 4][0];
        float4* u0p = (float4*)&u_s[wave][0];
        float4* u1p = (float4*)&u_s[wave + 4][0];
#pragma unroll 1
        for (int q = 0; q < 4; ++q) {
            const int n4 = lane + 64 * q;
            double4 acc0 = {0, 0, 0, 0}, acc1 = {0, 0, 0, 0};
            for (int m4 = 0; m4 < 64; ++m4) {
                float4 r0 = r0p[m4];
                float4 r1 = r1p[m4];
                float4 w0 = loadWT<T>(Wp, 4 * m4 + 0, n4);
                float4 w1 = loadWT<T>(Wp, 4 * m4 + 1, n4);
                float4 w2 = loadWT<T>(Wp, 4 * m4 + 2, n4);
                float4 w3 = loadWT<T>(Wp, 4 * m4 + 3, n4);
                DFMA4(acc0, r0.x, w0); DFMA4(acc0, r0.y, w1); DFMA4(acc0, r0.z, w2); DFMA4(acc0, r0.w, w3);
                DFMA4(acc1, r1.x, w0); DFMA4(acc1, r1.y, w1); DFMA4(acc1, r1.z, w2); DFMA4(acc1, r1.w, w3);
            }
            float4 uv0 = u0p[n4];
            uv0.x = (float)((double)uv0.x + acc0.x);
            uv0.y = (float)((double)uv0.y + acc0.y);
            uv0.z = (float)((double)uv0.z + acc0.z);
            uv0.w = (float)((double)uv0.w + acc0.w);
            u0p[n4] = uv0;
            float4 uv1 = u1p[n4];
            uv1.x = (float)((double)uv1.x + acc1.x);
            uv1.y = (float)((double)uv1.y + acc1.y);
            uv1.z = (float)((double)uv1.z + acc1.z);
            uv1.w = (float)((double)uv1.w + acc1.w);
            u1p[n4] = uv1;
        }
    }
    __syncthreads();
    {
#pragma unroll 1
        for (int rr = 0; rr < 2; ++rr) {
            const int row = wave + rr * 4;
            unsigned key[16];
#pragma unroll
            for (int j = 0; j < 16; ++j)
                key[j] = __float_as_uint(u_s[row][lane + 64 * j]) & 0x7fffffffu;
            unsigned p = 0;
#pragma unroll 1
            for (int b = 30; b >= 0; --b) {
                const unsigned cand = p | (1u << b);
                int cnt = 0;
#pragma unroll
                for (int j = 0; j < 16; ++j) cnt += (key[j] >= cand) ? 1 : 0;
#pragma unroll
                for (int off = 32; off; off >>= 1) cnt += __shfl_xor(cnt, off);
                if (cnt >= kth) p = cand;
            }
            if (lane == 0) tau_s[row] = __uint_as_float(p);
        }
    }
    __syncthreads();
    {
        const float4* us4 = (const float4*)&u_s[0][0];
        float4* Uw = (float4*)(U + (size_t)row0 * N_DIM);
#pragma unroll 1
        for (int c = 0; c < 8; ++c) {
            const int idx = tid + 256 * c;
            const int row = idx >> 8;
            const float thrv = fmaxf(t, tau_s[row]);
            float4 v = us4[idx];
            float4 o;
            o.x = shrink_one(v.x, t, thrv);
            o.y = shrink_one(v.y, t, thrv);
            o.z = shrink_one(v.z, t, thrv);
            o.w = shrink_one(v.w, t, thrv);
            Uw[idx] = o;
        }
    }
}

// ================= launcher =================
extern "C" void kernel_launch(void* const* d_in, const int* in_sizes, int n_in,
                              void* d_out, int out_size, void* d_ws, size_t ws_size,
                              hipStream_t stream) {
    const float* x   = (const float*)d_in[0];  // [16384][256]
    const float* A   = (const float*)d_in[1];  // [256][1024]
    const float* W   = (const float*)d_in[2];  // [16][1024][256]
    const float* thr = (const float*)d_in[3];  // [16]

    float* UV = (float*)d_out;                 // u / v state lives in d_out (f32)

    static const int ktab[DEPTH] = {13, 25, 37, 50, 52, 52, 52, 52,
                                    52, 52, 52, 52, 52, 52, 52, 52};

    if (ws_size >= WS_FAST_NEED) {
        unsigned short* ATp = (unsigned short*)((char*)d_ws + ATP_OFF_B);
        unsigned short* WTp = (unsigned short*)((char*)d_ws + WTP_OFF_B);
        float* R = (float*)((char*)d_ws + R_OFF_B);

        prep_a_kernel<<<128, 256, 0, stream>>>(A, ATp);
        prep_w_kernel<<<2048, 256, 0, stream>>>(W, WTp);

        for (int it = 0; it < DEPTH; ++it) {
            if (it > 0)
                g1_kernel<<<256, 1024, 0, stream>>>(UV, x, ATp, R);
            g2_kernel<<<1024, 1024, 0, stream>>>(it == 0 ? x : R,
                                                 WTp + (size_t)it * (64 * 8 * 3 * 512),
                                                 UV, it == 0 ? 1 : 0);
            s_kernel<<<B_ROWS / 8, 256, 0, stream>>>(UV, thr, it, ktab[it]);
        }
    } else if (ws_size >= WS_OLD_NEED) {
        float* ws = (float*)d_ws;
        float* AT = ws + AT_OFF;
        float* WT = ws + WT_OFF;
        zero_kernel<<<1024, 256, 0, stream>>>(UV, B_ROWS * N_DIM);
        dim3 tb(32, 8);
        transpose_kernel<<<dim3(N_DIM / 32, M_DIM / 32, 1), tb, 0, stream>>>(A, AT, M_DIM, N_DIM);
        transpose_kernel<<<dim3(M_DIM / 32, N_DIM / 32, DEPTH), tb, 0, stream>>>(W, WT, N_DIM, M_DIM);
        for (int it = 0; it < DEPTH; ++it)
            lista_iter_kernel<true><<<B_ROWS / 8, 256, 0, stream>>>(
                x, AT, WT + (size_t)it * M_DIM * N_DIM, thr, UV, it, ktab[it]);
    } else {
        zero_kernel<<<1024, 256, 0, stream>>>(UV, B_ROWS * N_DIM);
        for (int it = 0; it < DEPTH; ++it)
            lista_iter_kernel<false><<<B_ROWS / 8, 256, 0, stream>>>(
                x, A, W + (size_t)it * N_DIM * M_DIM, thr, UV, it, ktab[it]);
    }
}